// Round 1
// baseline (319.433 us; speedup 1.0000x reference)
//
#include <hip/hip_runtime.h>
#include <hip/hip_bf16.h>

#define SEQ 2048
#define BATCH 2
#define IN_DIM 512
#define EMBED 512
#define HEADS 8
#define HD 64
#define N3 1536

using f32x4 = __attribute__((ext_vector_type(4))) float;
using s16x8 = __attribute__((ext_vector_type(8))) short;

__device__ __forceinline__ unsigned short f2bf(float f) {
    union { float f; unsigned int u; } v; v.f = f;
    unsigned int u = v.u;
    unsigned int r = (u + 0x7FFFu + ((u >> 16) & 1u)) >> 16;
    return (unsigned short)r;
}

// ---------------- Kernel 1: QKV projection ----------------
// C[4096][1536] = xb[4096][512] @ Wqkv[512][1536] + bqkv
// xb row m -> x[s][b][:] with b = m>>11, s = m&2047
// Writes Qb[b][h][s][d], Kb[b][h][s][d], Vt[b][h][d][s] (bf16)
__global__ __launch_bounds__(256) void qkv_proj(
    const float* __restrict__ x, const float* __restrict__ Wqkv,
    const float* __restrict__ bqkv,
    unsigned short* __restrict__ Qb, unsigned short* __restrict__ Kb,
    unsigned short* __restrict__ Vt)
{
    __shared__ __align__(16) unsigned short As[64][72];
    __shared__ __align__(16) unsigned short Bs[64][72];
    const int bm = blockIdx.x, bn = blockIdx.y;
    const int tid = threadIdx.x;
    const int lane = tid & 63, w = tid >> 6;
    const int fr = lane & 15, fg = lane >> 4;
    const int m0 = bm * 64, n0 = bn * 64;
    const int ri = tid >> 2;          // row within 64-tile
    const int cj = (tid & 3) * 16;    // col start within 64-tile

    f32x4 acc[4];
#pragma unroll
    for (int t = 0; t < 4; t++) acc[t] = (f32x4){0.f, 0.f, 0.f, 0.f};

    const int gm = m0 + ri;
    const int b_ = gm >> 11, s_ = gm & 2047;
    const float* xrow = x + ((size_t)s_ * BATCH + b_) * IN_DIM;

    for (int k0 = 0; k0 < IN_DIM; k0 += 64) {
        // stage A (x -> bf16), k contiguous
        {
            const float4* src = reinterpret_cast<const float4*>(xrow + k0 + cj);
#pragma unroll
            for (int v = 0; v < 4; v++) {
                float4 f = src[v];
                ushort4 u;
                u.x = f2bf(f.x); u.y = f2bf(f.y); u.z = f2bf(f.z); u.w = f2bf(f.w);
                *reinterpret_cast<ushort4*>(&As[ri][cj + 4 * v]) = u;
            }
        }
        // stage B transposed: Bs[n][k]
        {
            const float4* src = reinterpret_cast<const float4*>(Wqkv + (size_t)(k0 + ri) * N3 + n0 + cj);
#pragma unroll
            for (int v = 0; v < 4; v++) {
                float4 f = src[v];
                Bs[cj + 4 * v + 0][ri] = f2bf(f.x);
                Bs[cj + 4 * v + 1][ri] = f2bf(f.y);
                Bs[cj + 4 * v + 2][ri] = f2bf(f.z);
                Bs[cj + 4 * v + 3][ri] = f2bf(f.w);
            }
        }
        __syncthreads();
#pragma unroll
        for (int h2 = 0; h2 < 2; h2++) {
            s16x8 a = *reinterpret_cast<const s16x8*>(&As[w * 16 + fr][h2 * 32 + fg * 8]);
#pragma unroll
            for (int t = 0; t < 4; t++) {
                s16x8 b = *reinterpret_cast<const s16x8*>(&Bs[t * 16 + fr][h2 * 32 + fg * 8]);
                acc[t] = __builtin_amdgcn_mfma_f32_16x16x32_bf16(a, b, acc[t], 0, 0, 0);
            }
        }
        __syncthreads();
    }

    // epilogue: route to Q/K/V
#pragma unroll
    for (int t = 0; t < 4; t++) {
        const int col = n0 + t * 16 + fr;
        const int h = col / 192, r = col % 192;
        const float bq = bqkv[col];
#pragma unroll
        for (int j = 0; j < 4; j++) {
            const int grow = m0 + w * 16 + fg * 4 + j;
            const int bo_ = grow >> 11, so_ = grow & 2047;
            const unsigned short bv = f2bf(acc[t][j] + bq);
            if (r < 64)
                Qb[(((size_t)bo_ * HEADS + h) * SEQ + so_) * HD + r] = bv;
            else if (r < 128)
                Kb[(((size_t)bo_ * HEADS + h) * SEQ + so_) * HD + (r - 64)] = bv;
            else
                Vt[(((size_t)bo_ * HEADS + h) * HD + (r - 128)) * SEQ + so_] = bv;
        }
    }
}

// ---------------- Kernel 2: flash attention ----------------
// One block per (h, q-tile of 64). Both batches in one block (bias read once).
// 4 waves, wave w owns Q rows [q0+16w, q0+16w+16).
__global__ __launch_bounds__(256) void flash_attn(
    const unsigned short* __restrict__ Qb, const unsigned short* __restrict__ Kb,
    const unsigned short* __restrict__ Vt, const float* __restrict__ bias,
    unsigned short* __restrict__ Ob)
{
    __shared__ __align__(16) unsigned short Ks[2][64][72];
    __shared__ __align__(16) unsigned short Vs[2][64][72];   // [b][d][key]
    __shared__ __align__(16) unsigned short Ps[4][16][72];   // per-wave P
    const int h = blockIdx.y;
    const int q0 = blockIdx.x * 64;
    const int tid = threadIdx.x, lane = tid & 63, w = tid >> 6;
    const int fr = lane & 15, fg = lane >> 4;
    const int ri = tid >> 2, cj = (tid & 3) * 16;

    // preload Q fragments (row = q0 + 16w + fr)
    s16x8 qf[2][2];
#pragma unroll
    for (int b = 0; b < 2; b++) {
        const unsigned short* qrow = Qb + (((size_t)b * HEADS + h) * SEQ + q0 + w * 16 + fr) * HD;
#pragma unroll
        for (int h2 = 0; h2 < 2; h2++)
            qf[b][h2] = *reinterpret_cast<const s16x8*>(qrow + h2 * 32 + fg * 8);
    }

    float mrow[2][4], lrow[2][4];
    f32x4 oacc[2][4];
#pragma unroll
    for (int b = 0; b < 2; b++)
#pragma unroll
        for (int j = 0; j < 4; j++) { mrow[b][j] = -1e30f; lrow[b][j] = 0.f; }
#pragma unroll
    for (int b = 0; b < 2; b++)
#pragma unroll
        for (int t = 0; t < 4; t++) oacc[b][t] = (f32x4){0.f, 0.f, 0.f, 0.f};

    const float scale = 0.08838834764831845f; // 1/sqrt(2*64)

    for (int k0 = 0; k0 < SEQ; k0 += 64) {
        // stage K and V^T tiles for both batches
#pragma unroll
        for (int b = 0; b < 2; b++) {
            const unsigned short* ksrc = Kb + (((size_t)b * HEADS + h) * SEQ + k0 + ri) * HD + cj;
            *reinterpret_cast<uint4*>(&Ks[b][ri][cj])     = *reinterpret_cast<const uint4*>(ksrc);
            *reinterpret_cast<uint4*>(&Ks[b][ri][cj + 8]) = *reinterpret_cast<const uint4*>(ksrc + 8);
            const unsigned short* vsrc = Vt + (((size_t)b * HEADS + h) * HD + ri) * SEQ + k0 + cj;
            *reinterpret_cast<uint4*>(&Vs[b][ri][cj])     = *reinterpret_cast<const uint4*>(vsrc);
            *reinterpret_cast<uint4*>(&Vs[b][ri][cj + 8]) = *reinterpret_cast<const uint4*>(vsrc + 8);
        }
        __syncthreads();

        // bias tile (shared by both batches)
        float biasr[4][4];
#pragma unroll
        for (int t = 0; t < 4; t++)
#pragma unroll
            for (int j = 0; j < 4; j++) {
                const int grow = q0 + w * 16 + fg * 4 + j;
                biasr[t][j] = bias[((size_t)h * SEQ + grow) * SEQ + k0 + t * 16 + fr];
            }

#pragma unroll
        for (int b = 0; b < 2; b++) {
            f32x4 sacc[4];
#pragma unroll
            for (int t = 0; t < 4; t++) sacc[t] = (f32x4){0.f, 0.f, 0.f, 0.f};
#pragma unroll
            for (int h2 = 0; h2 < 2; h2++) {
                s16x8 a = qf[b][h2];
#pragma unroll
                for (int t = 0; t < 4; t++) {
                    s16x8 kf = *reinterpret_cast<const s16x8*>(&Ks[b][t * 16 + fr][h2 * 32 + fg * 8]);
                    sacc[t] = __builtin_amdgcn_mfma_f32_16x16x32_bf16(a, kf, sacc[t], 0, 0, 0);
                }
            }
            // scale + bias
#pragma unroll
            for (int t = 0; t < 4; t++)
#pragma unroll
                for (int j = 0; j < 4; j++)
                    sacc[t][j] = sacc[t][j] * scale + biasr[t][j];
            // row max (across 4 tiles, then across 16 lanes of group)
            float fac[4];
#pragma unroll
            for (int j = 0; j < 4; j++) {
                float m = fmaxf(fmaxf(sacc[0][j], sacc[1][j]), fmaxf(sacc[2][j], sacc[3][j]));
#pragma unroll
                for (int msk = 1; msk < 16; msk <<= 1) m = fmaxf(m, __shfl_xor(m, msk, 64));
                const float newm = fmaxf(mrow[b][j], m);
                fac[j] = __expf(mrow[b][j] - newm);
                mrow[b][j] = newm;
            }
            // exp
#pragma unroll
            for (int t = 0; t < 4; t++)
#pragma unroll
                for (int j = 0; j < 4; j++)
                    sacc[t][j] = __expf(sacc[t][j] - mrow[b][j]);
            // row sum
#pragma unroll
            for (int j = 0; j < 4; j++) {
                float s = sacc[0][j] + sacc[1][j] + sacc[2][j] + sacc[3][j];
#pragma unroll
                for (int msk = 1; msk < 16; msk <<= 1) s += __shfl_xor(s, msk, 64);
                lrow[b][j] = lrow[b][j] * fac[j] + s;
            }
            // P -> LDS (bf16), re-layout for A-fragment reads
#pragma unroll
            for (int t = 0; t < 4; t++)
#pragma unroll
                for (int j = 0; j < 4; j++)
                    Ps[w][fg * 4 + j][t * 16 + fr] = f2bf(sacc[t][j]);
            // rescale O
#pragma unroll
            for (int t = 0; t < 4; t++)
#pragma unroll
                for (int j = 0; j < 4; j++)
                    oacc[b][t][j] *= fac[j];
            // PV
#pragma unroll
            for (int h2 = 0; h2 < 2; h2++) {
                s16x8 pa = *reinterpret_cast<const s16x8*>(&Ps[w][fr][h2 * 32 + fg * 8]);
#pragma unroll
                for (int t = 0; t < 4; t++) {
                    s16x8 vf = *reinterpret_cast<const s16x8*>(&Vs[b][t * 16 + fr][h2 * 32 + fg * 8]);
                    oacc[b][t] = __builtin_amdgcn_mfma_f32_16x16x32_bf16(pa, vf, oacc[b][t], 0, 0, 0);
                }
            }
        }
        __syncthreads();
    }

    // epilogue: O / l -> Ob[b][s][h*64+d]  (bf16)
#pragma unroll
    for (int b = 0; b < 2; b++)
#pragma unroll
        for (int t = 0; t < 4; t++)
#pragma unroll
            for (int j = 0; j < 4; j++) {
                const int grow = q0 + w * 16 + fg * 4 + j;
                const float o = oacc[b][t][j] / lrow[b][j];
                Ob[((size_t)b * SEQ + grow) * EMBED + h * HD + t * 16 + fr] = f2bf(o);
            }
}

// ---------------- Kernel 3: output projection ----------------
// out[4096][512] = Ob[4096][512] @ Wo[512][512] + bo   (fp32 out)
__global__ __launch_bounds__(256) void out_proj(
    const unsigned short* __restrict__ Ao, const float* __restrict__ Wo,
    const float* __restrict__ bo, float* __restrict__ out)
{
    __shared__ __align__(16) unsigned short As[64][72];
    __shared__ __align__(16) unsigned short Bs[64][72];
    const int bm = blockIdx.x, bn = blockIdx.y;
    const int tid = threadIdx.x, lane = tid & 63, w = tid >> 6;
    const int fr = lane & 15, fg = lane >> 4;
    const int m0 = bm * 64, n0 = bn * 64;
    const int ri = tid >> 2, cj = (tid & 3) * 16;

    f32x4 acc[4];
#pragma unroll
    for (int t = 0; t < 4; t++) acc[t] = (f32x4){0.f, 0.f, 0.f, 0.f};

    for (int k0 = 0; k0 < EMBED; k0 += 64) {
        const unsigned short* asrc = Ao + (size_t)(m0 + ri) * EMBED + k0 + cj;
        *reinterpret_cast<uint4*>(&As[ri][cj])     = *reinterpret_cast<const uint4*>(asrc);
        *reinterpret_cast<uint4*>(&As[ri][cj + 8]) = *reinterpret_cast<const uint4*>(asrc + 8);
        const float4* bsrc = reinterpret_cast<const float4*>(Wo + (size_t)(k0 + ri) * EMBED + n0 + cj);
#pragma unroll
        for (int v = 0; v < 4; v++) {
            float4 f = bsrc[v];
            Bs[cj + 4 * v + 0][ri] = f2bf(f.x);
            Bs[cj + 4 * v + 1][ri] = f2bf(f.y);
            Bs[cj + 4 * v + 2][ri] = f2bf(f.z);
            Bs[cj + 4 * v + 3][ri] = f2bf(f.w);
        }
        __syncthreads();
#pragma unroll
        for (int h2 = 0; h2 < 2; h2++) {
            s16x8 a = *reinterpret_cast<const s16x8*>(&As[w * 16 + fr][h2 * 32 + fg * 8]);
#pragma unroll
            for (int t = 0; t < 4; t++) {
                s16x8 b = *reinterpret_cast<const s16x8*>(&Bs[t * 16 + fr][h2 * 32 + fg * 8]);
                acc[t] = __builtin_amdgcn_mfma_f32_16x16x32_bf16(a, b, acc[t], 0, 0, 0);
            }
        }
        __syncthreads();
    }

#pragma unroll
    for (int t = 0; t < 4; t++) {
        const int col = n0 + t * 16 + fr;
        const float bb = bo[col];
#pragma unroll
        for (int j = 0; j < 4; j++) {
            const int grow = m0 + w * 16 + fg * 4 + j;
            out[(size_t)grow * EMBED + col] = acc[t][j] + bb;
        }
    }
}

extern "C" void kernel_launch(void* const* d_in, const int* in_sizes, int n_in,
                              void* d_out, int out_size, void* d_ws, size_t ws_size,
                              hipStream_t stream) {
    const float* x    = (const float*)d_in[0];
    const float* bias = (const float*)d_in[1];
    const float* Wqkv = (const float*)d_in[2];
    const float* bqkv = (const float*)d_in[3];
    const float* Wo   = (const float*)d_in[4];
    const float* bo   = (const float*)d_in[5];
    float* out = (float*)d_out;

    const size_t perT = (size_t)BATCH * HEADS * SEQ * HD; // 2M elems
    unsigned short* Qb = (unsigned short*)d_ws;
    unsigned short* Kb = Qb + perT;
    unsigned short* Vt = Kb + perT;
    unsigned short* Ob = Vt + perT;

    qkv_proj<<<dim3(64, 24), 256, 0, stream>>>(x, Wqkv, bqkv, Qb, Kb, Vt);
    flash_attn<<<dim3(32, 8), 256, 0, stream>>>(Qb, Kb, Vt, bias, Ob);
    out_proj<<<dim3(64, 8), 256, 0, stream>>>(Ob, Wo, bo, out);
}

// Round 2
// 266.119 us; speedup vs baseline: 1.2003x; 1.2003x over previous
//
#include <hip/hip_runtime.h>
#include <hip/hip_bf16.h>

#define SEQ 2048
#define BATCH 2
#define IN_DIM 512
#define EMBED 512
#define HEADS 8
#define HD 64
#define N3 1536

using f32x4 = __attribute__((ext_vector_type(4))) float;
using s16x8 = __attribute__((ext_vector_type(8))) short;

__device__ __forceinline__ unsigned short f2bf(float f) {
    union { float f; unsigned int u; } v; v.f = f;
    unsigned int u = v.u;
    unsigned int r = (u + 0x7FFFu + ((u >> 16) & 1u)) >> 16;
    return (unsigned short)r;
}

// ---------- prep: x [S][B][D] fp32 -> Ab [B*S][D] bf16 ----------
__global__ __launch_bounds__(256) void prep_x(
    const float* __restrict__ x, unsigned short* __restrict__ Ab)
{
    const int gid = blockIdx.x * 256 + threadIdx.x;
    const int base = gid * 4;
    const int m = base >> 9, k = base & 511;
    const int b = m >> 11, s = m & 2047;
    float4 f = *reinterpret_cast<const float4*>(x + ((size_t)s * BATCH + b) * IN_DIM + k);
    ushort4 u;
    u.x = f2bf(f.x); u.y = f2bf(f.y); u.z = f2bf(f.z); u.w = f2bf(f.w);
    *reinterpret_cast<ushort4*>(Ab + (size_t)m * IN_DIM + k) = u;
}

// ---------- prep: transpose fp32 [K][N] -> bf16 [N][K] ----------
__global__ __launch_bounds__(256) void transpose_w(
    const float* __restrict__ in, unsigned short* __restrict__ out, int K, int N)
{
    __shared__ __align__(16) unsigned short T[64][72];
    const int k0 = blockIdx.x * 64, n0 = blockIdx.y * 64;
    const int tid = threadIdx.x;
    const int ri = tid >> 2, cj = (tid & 3) * 16;
#pragma unroll
    for (int v = 0; v < 4; v++) {
        float4 f = *reinterpret_cast<const float4*>(in + (size_t)(k0 + ri) * N + n0 + cj + 4 * v);
        T[cj + 4 * v + 0][ri] = f2bf(f.x);
        T[cj + 4 * v + 1][ri] = f2bf(f.y);
        T[cj + 4 * v + 2][ri] = f2bf(f.z);
        T[cj + 4 * v + 3][ri] = f2bf(f.w);
    }
    __syncthreads();
    unsigned short* dst = out + (size_t)(n0 + ri) * K + k0 + cj;
    *reinterpret_cast<uint4*>(dst)     = *reinterpret_cast<const uint4*>(&T[ri][cj]);
    *reinterpret_cast<uint4*>(dst + 8) = *reinterpret_cast<const uint4*>(&T[ri][cj + 8]);
}

// ---------------- Kernel 1: QKV projection (all bf16) ----------------
// C[4096][1536] = Ab[4096][512] @ Wt[1536][512]^T + bqkv
// Writes Qb[b][h][s][d], Kb[b][h][s][d], Vt[b][h][d][s]
__global__ __launch_bounds__(256) void qkv_proj(
    const unsigned short* __restrict__ Ab, const unsigned short* __restrict__ Wt,
    const float* __restrict__ bqkv,
    unsigned short* __restrict__ Qb, unsigned short* __restrict__ Kb,
    unsigned short* __restrict__ Vt)
{
    __shared__ __align__(16) unsigned short As[64][72];
    __shared__ __align__(16) unsigned short Bs[64][72];
    const int bm = blockIdx.x, bn = blockIdx.y;
    const int tid = threadIdx.x;
    const int lane = tid & 63, w = tid >> 6;
    const int fr = lane & 15, fg = lane >> 4;
    const int m0 = bm * 64, n0 = bn * 64;
    const int ri = tid >> 2, cj = (tid & 3) * 16;

    f32x4 acc[4];
#pragma unroll
    for (int t = 0; t < 4; t++) acc[t] = (f32x4){0.f, 0.f, 0.f, 0.f};

    for (int k0 = 0; k0 < IN_DIM; k0 += 64) {
        const unsigned short* asrc = Ab + (size_t)(m0 + ri) * IN_DIM + k0 + cj;
        *reinterpret_cast<uint4*>(&As[ri][cj])     = *reinterpret_cast<const uint4*>(asrc);
        *reinterpret_cast<uint4*>(&As[ri][cj + 8]) = *reinterpret_cast<const uint4*>(asrc + 8);
        const unsigned short* bsrc = Wt + (size_t)(n0 + ri) * IN_DIM + k0 + cj;
        *reinterpret_cast<uint4*>(&Bs[ri][cj])     = *reinterpret_cast<const uint4*>(bsrc);
        *reinterpret_cast<uint4*>(&Bs[ri][cj + 8]) = *reinterpret_cast<const uint4*>(bsrc + 8);
        __syncthreads();
#pragma unroll
        for (int h2 = 0; h2 < 2; h2++) {
            s16x8 a = *reinterpret_cast<const s16x8*>(&As[w * 16 + fr][h2 * 32 + fg * 8]);
#pragma unroll
            for (int t = 0; t < 4; t++) {
                s16x8 b = *reinterpret_cast<const s16x8*>(&Bs[t * 16 + fr][h2 * 32 + fg * 8]);
                acc[t] = __builtin_amdgcn_mfma_f32_16x16x32_bf16(a, b, acc[t], 0, 0, 0);
            }
        }
        __syncthreads();
    }

    // epilogue: per-block-uniform routing. col = bn*64 + t*16+fr, h = bn/3, route = bn%3
    const int h = bn / 3, route = bn % 3;
    const int b_ = m0 >> 11, s0 = m0 & 2047;
    if (route < 2) {
        unsigned short* dst = (route == 0) ? Qb : Kb;
#pragma unroll
        for (int t = 0; t < 4; t++) {
            const int d = t * 16 + fr;
            const float bq = bqkv[n0 + t * 16 + fr];
#pragma unroll
            for (int j = 0; j < 4; j++) {
                const int sl = s0 + w * 16 + fg * 4 + j;
                dst[(((size_t)b_ * HEADS + h) * SEQ + sl) * HD + d] = f2bf(acc[t][j] + bq);
            }
        }
    } else {
        // V: transpose through LDS (reuse As), write Vt[b][h][d][s] coalesced
#pragma unroll
        for (int t = 0; t < 4; t++) {
            const float bq = bqkv[n0 + t * 16 + fr];
#pragma unroll
            for (int j = 0; j < 4; j++)
                As[t * 16 + fr][w * 16 + fg * 4 + j] = f2bf(acc[t][j] + bq);
        }
        __syncthreads();
        unsigned short* dst = Vt + (((size_t)b_ * HEADS + h) * HD + ri) * SEQ + s0 + cj;
        *reinterpret_cast<uint4*>(dst)     = *reinterpret_cast<const uint4*>(&As[ri][cj]);
        *reinterpret_cast<uint4*>(dst + 8) = *reinterpret_cast<const uint4*>(&As[ri][cj + 8]);
    }
}

// ---------------- Kernel 2: flash attention ----------------
// grid (32, 8, 2): q-tile 64, head, batch. 4 waves, wave w owns rows [q0+16w, q0+16w+16).
// Double-buffered K/V LDS + reg-prefetched bias (one k-step ahead).
__global__ __launch_bounds__(256) void flash_attn(
    const unsigned short* __restrict__ Qb, const unsigned short* __restrict__ Kb,
    const unsigned short* __restrict__ Vt, const float* __restrict__ bias,
    unsigned short* __restrict__ Ob)
{
    __shared__ __align__(16) unsigned short Ks[2][64][72];
    __shared__ __align__(16) unsigned short Vs[2][64][72];   // [d][key]
    __shared__ __align__(16) unsigned short Ps[4][16][72];
    const int h = blockIdx.y, b = blockIdx.z;
    const int q0 = blockIdx.x * 64;
    const int tid = threadIdx.x, lane = tid & 63, w = tid >> 6;
    const int fr = lane & 15, fg = lane >> 4;

    const unsigned short* Kbase = Kb + (size_t)(b * HEADS + h) * SEQ * HD;
    const unsigned short* Vbase = Vt + (size_t)(b * HEADS + h) * HD * SEQ;
    const float* bbase = bias + (size_t)h * SEQ * SEQ + (size_t)q0 * SEQ;

    // Q fragments (row = q0 + 16w + fr)
    const unsigned short* qrow = Qb + ((size_t)(b * HEADS + h) * SEQ + q0 + w * 16 + fr) * HD;
    s16x8 qf0 = *reinterpret_cast<const s16x8*>(qrow + fg * 8);
    s16x8 qf1 = *reinterpret_cast<const s16x8*>(qrow + 32 + fg * 8);

    // staging slots: each thread stages 2 uint4 per tensor
    const int r0 = tid >> 3, c0 = (tid & 7) * 8;
    const int r1 = r0 + 32;

    uint4 kr0, kr1, vr0, vr1;
    float bA[4][4], bB[4][4];

    // prologue: tile 0
    kr0 = *reinterpret_cast<const uint4*>(Kbase + (size_t)r0 * HD + c0);
    kr1 = *reinterpret_cast<const uint4*>(Kbase + (size_t)r1 * HD + c0);
    vr0 = *reinterpret_cast<const uint4*>(Vbase + (size_t)r0 * SEQ + c0);
    vr1 = *reinterpret_cast<const uint4*>(Vbase + (size_t)r1 * SEQ + c0);
#pragma unroll
    for (int t = 0; t < 4; t++)
#pragma unroll
        for (int j = 0; j < 4; j++)
            bA[t][j] = bbase[(size_t)(w * 16 + fg * 4 + j) * SEQ + t * 16 + fr];
    *reinterpret_cast<uint4*>(&Ks[0][r0][c0]) = kr0;
    *reinterpret_cast<uint4*>(&Ks[0][r1][c0]) = kr1;
    *reinterpret_cast<uint4*>(&Vs[0][r0][c0]) = vr0;
    *reinterpret_cast<uint4*>(&Vs[0][r1][c0]) = vr1;
    __syncthreads();

    float mrow[4], lrow[4];
    f32x4 oacc[4];
#pragma unroll
    for (int j = 0; j < 4; j++) { mrow[j] = -1e30f; lrow[j] = 0.f; }
#pragma unroll
    for (int t = 0; t < 4; t++) oacc[t] = (f32x4){0.f, 0.f, 0.f, 0.f};

    const float scale = 0.08838834764831845f; // 1/sqrt(2*64)

    auto body = [&](int n, const float (&bc)[4][4], float (&bnx)[4][4]) {
        const int cur = n & 1;
        const bool pf = (n < 31);
        const int kn = (n + 1) * 64;
        if (pf) {
            kr0 = *reinterpret_cast<const uint4*>(Kbase + (size_t)(kn + r0) * HD + c0);
            kr1 = *reinterpret_cast<const uint4*>(Kbase + (size_t)(kn + r1) * HD + c0);
            vr0 = *reinterpret_cast<const uint4*>(Vbase + (size_t)r0 * SEQ + kn + c0);
            vr1 = *reinterpret_cast<const uint4*>(Vbase + (size_t)r1 * SEQ + kn + c0);
#pragma unroll
            for (int t = 0; t < 4; t++)
#pragma unroll
                for (int j = 0; j < 4; j++)
                    bnx[t][j] = bbase[(size_t)(w * 16 + fg * 4 + j) * SEQ + kn + t * 16 + fr];
        }
        // QK^T
        f32x4 sacc[4];
#pragma unroll
        for (int t = 0; t < 4; t++) sacc[t] = (f32x4){0.f, 0.f, 0.f, 0.f};
#pragma unroll
        for (int h2 = 0; h2 < 2; h2++) {
            s16x8 a = (h2 == 0) ? qf0 : qf1;
#pragma unroll
            for (int t = 0; t < 4; t++) {
                s16x8 kf = *reinterpret_cast<const s16x8*>(&Ks[cur][t * 16 + fr][h2 * 32 + fg * 8]);
                sacc[t] = __builtin_amdgcn_mfma_f32_16x16x32_bf16(a, kf, sacc[t], 0, 0, 0);
            }
        }
#pragma unroll
        for (int t = 0; t < 4; t++)
#pragma unroll
            for (int j = 0; j < 4; j++)
                sacc[t][j] = sacc[t][j] * scale + bc[t][j];
        // online softmax over row (16 lanes of group hold 64 cols)
        float fac[4];
#pragma unroll
        for (int j = 0; j < 4; j++) {
            float m = fmaxf(fmaxf(sacc[0][j], sacc[1][j]), fmaxf(sacc[2][j], sacc[3][j]));
#pragma unroll
            for (int msk = 1; msk < 16; msk <<= 1) m = fmaxf(m, __shfl_xor(m, msk, 64));
            const float newm = fmaxf(mrow[j], m);
            fac[j] = __expf(mrow[j] - newm);
            mrow[j] = newm;
        }
#pragma unroll
        for (int t = 0; t < 4; t++)
#pragma unroll
            for (int j = 0; j < 4; j++)
                sacc[t][j] = __expf(sacc[t][j] - mrow[j]);
#pragma unroll
        for (int j = 0; j < 4; j++) {
            float s = sacc[0][j] + sacc[1][j] + sacc[2][j] + sacc[3][j];
#pragma unroll
            for (int msk = 1; msk < 16; msk <<= 1) s += __shfl_xor(s, msk, 64);
            lrow[j] = lrow[j] * fac[j] + s;
        }
        // P -> per-wave LDS (re-layout to A-fragment)
#pragma unroll
        for (int t = 0; t < 4; t++)
#pragma unroll
            for (int j = 0; j < 4; j++)
                Ps[w][fg * 4 + j][t * 16 + fr] = f2bf(sacc[t][j]);
#pragma unroll
        for (int t = 0; t < 4; t++)
#pragma unroll
            for (int j = 0; j < 4; j++)
                oacc[t][j] *= fac[j];
        // PV
#pragma unroll
        for (int h2 = 0; h2 < 2; h2++) {
            s16x8 pa = *reinterpret_cast<const s16x8*>(&Ps[w][fr][h2 * 32 + fg * 8]);
#pragma unroll
            for (int t = 0; t < 4; t++) {
                s16x8 vf = *reinterpret_cast<const s16x8*>(&Vs[cur][t * 16 + fr][h2 * 32 + fg * 8]);
                oacc[t] = __builtin_amdgcn_mfma_f32_16x16x32_bf16(pa, vf, oacc[t], 0, 0, 0);
            }
        }
        // write prefetched tile into other buffer
        if (pf) {
            const int nxt = cur ^ 1;
            *reinterpret_cast<uint4*>(&Ks[nxt][r0][c0]) = kr0;
            *reinterpret_cast<uint4*>(&Ks[nxt][r1][c0]) = kr1;
            *reinterpret_cast<uint4*>(&Vs[nxt][r0][c0]) = vr0;
            *reinterpret_cast<uint4*>(&Vs[nxt][r1][c0]) = vr1;
        }
        __syncthreads();
    };

    for (int n = 0; n < 32; n += 2) {
        body(n, bA, bB);
        body(n + 1, bB, bA);
    }

    // epilogue
#pragma unroll
    for (int t = 0; t < 4; t++)
#pragma unroll
        for (int j = 0; j < 4; j++) {
            const int grow = q0 + w * 16 + fg * 4 + j;
            const float o = oacc[t][j] / lrow[j];
            Ob[((size_t)b * SEQ + grow) * EMBED + h * HD + t * 16 + fr] = f2bf(o);
        }
}

// ---------------- Kernel 3: output projection ----------------
// out[4096][512] = Ob[4096][512] @ Wot[512][512]^T + bo   (fp32 out)
__global__ __launch_bounds__(256) void out_proj(
    const unsigned short* __restrict__ Ao, const unsigned short* __restrict__ Wot,
    const float* __restrict__ bo, float* __restrict__ out)
{
    __shared__ __align__(16) unsigned short As[64][72];
    __shared__ __align__(16) unsigned short Bs[64][72];
    const int bm = blockIdx.x, bn = blockIdx.y;
    const int tid = threadIdx.x, lane = tid & 63, w = tid >> 6;
    const int fr = lane & 15, fg = lane >> 4;
    const int m0 = bm * 64, n0 = bn * 64;
    const int ri = tid >> 2, cj = (tid & 3) * 16;

    f32x4 acc[4];
#pragma unroll
    for (int t = 0; t < 4; t++) acc[t] = (f32x4){0.f, 0.f, 0.f, 0.f};

    for (int k0 = 0; k0 < EMBED; k0 += 64) {
        const unsigned short* asrc = Ao + (size_t)(m0 + ri) * EMBED + k0 + cj;
        *reinterpret_cast<uint4*>(&As[ri][cj])     = *reinterpret_cast<const uint4*>(asrc);
        *reinterpret_cast<uint4*>(&As[ri][cj + 8]) = *reinterpret_cast<const uint4*>(asrc + 8);
        const unsigned short* bsrc = Wot + (size_t)(n0 + ri) * EMBED + k0 + cj;
        *reinterpret_cast<uint4*>(&Bs[ri][cj])     = *reinterpret_cast<const uint4*>(bsrc);
        *reinterpret_cast<uint4*>(&Bs[ri][cj + 8]) = *reinterpret_cast<const uint4*>(bsrc + 8);
        __syncthreads();
#pragma unroll
        for (int h2 = 0; h2 < 2; h2++) {
            s16x8 a = *reinterpret_cast<const s16x8*>(&As[w * 16 + fr][h2 * 32 + fg * 8]);
#pragma unroll
            for (int t = 0; t < 4; t++) {
                s16x8 b = *reinterpret_cast<const s16x8*>(&Bs[t * 16 + fr][h2 * 32 + fg * 8]);
                acc[t] = __builtin_amdgcn_mfma_f32_16x16x32_bf16(a, b, acc[t], 0, 0, 0);
            }
        }
        __syncthreads();
    }

#pragma unroll
    for (int t = 0; t < 4; t++) {
        const int col = n0 + t * 16 + fr;
        const float bb = bo[col];
#pragma unroll
        for (int j = 0; j < 4; j++) {
            const int grow = m0 + w * 16 + fg * 4 + j;
            out[(size_t)grow * EMBED + col] = acc[t][j] + bb;
        }
    }
}

extern "C" void kernel_launch(void* const* d_in, const int* in_sizes, int n_in,
                              void* d_out, int out_size, void* d_ws, size_t ws_size,
                              hipStream_t stream) {
    const float* x    = (const float*)d_in[0];
    const float* bias = (const float*)d_in[1];
    const float* Wqkv = (const float*)d_in[2];
    const float* bqkv = (const float*)d_in[3];
    const float* Wo   = (const float*)d_in[4];
    const float* bo   = (const float*)d_in[5];
    float* out = (float*)d_out;

    const size_t perT = (size_t)BATCH * HEADS * SEQ * HD; // 2M elems
    unsigned short* Qb    = (unsigned short*)d_ws;
    unsigned short* Kb    = Qb + perT;
    unsigned short* Vt    = Kb + perT;
    unsigned short* Ob    = Vt + perT;
    unsigned short* Ab    = Ob + perT;                        // 2M
    unsigned short* Wqkvt = Ab + (size_t)BATCH * SEQ * IN_DIM; // 1536*512
    unsigned short* Wot   = Wqkvt + (size_t)N3 * IN_DIM;       // 512*512

    prep_x<<<2048, 256, 0, stream>>>(x, Ab);
    transpose_w<<<dim3(8, 24), 256, 0, stream>>>(Wqkv, Wqkvt, IN_DIM, N3);
    transpose_w<<<dim3(8, 8), 256, 0, stream>>>(Wo, Wot, EMBED, EMBED);
    qkv_proj<<<dim3(64, 24), 256, 0, stream>>>(Ab, Wqkvt, bqkv, Qb, Kb, Vt);
    flash_attn<<<dim3(32, 8, 2), 256, 0, stream>>>(Qb, Kb, Vt, bias, Ob);
    out_proj<<<dim3(64, 8), 256, 0, stream>>>(Ob, Wot, bo, out);
}